// Round 6
// baseline (275.607 us; speedup 1.0000x reference)
//
#include <hip/hip_runtime.h>
#include <math.h>

#define NB   128
#define CF   1024
#define RR   256
#define NA   312
#define DV   300
#define MT   640
#define NKC  32
#define NQ   160
#define NPI  320          // padded i-pairs
#define ABYTES 40960      // A tile: 640 rows x 64 B (f16)
#define BHB    8192       // B tile: [4 fq][128 r][16 B] f16
#define BUFSZ  49152      // ABYTES + BHB

typedef _Float16 half8  __attribute__((ext_vector_type(8)));
typedef _Float16 half4  __attribute__((ext_vector_type(4)));
typedef float float16v  __attribute__((ext_vector_type(16)));
typedef float float4v   __attribute__((ext_vector_type(4)));

// async global->LDS, 16B/lane; dest = wave-uniform base + lane*16 (linear).
__device__ __forceinline__ void gll16(const void* g, void* l) {
    __builtin_amdgcn_global_load_lds(
        (const __attribute__((address_space(1))) void*)g,
        (__attribute__((address_space(3))) void*)l, 16, 0, 0);
}

// ---- K0: Q projection (pair-interleaved Qb rows: row 2i = Q1_i, 2i+1 = Q2_i) ----
__launch_bounds__(256, 4)
__global__ void k_q(const float* __restrict__ V, const float* __restrict__ W1,
                    const float* __restrict__ W2, _Float16* __restrict__ Qb) {
    int ib = blockIdx.x;
    int t  = threadIdx.x;
    bool isQ2 = ib >= 80;
    int i0l = (ib - (isQ2 ? 80 : 0)) * 4;
    __shared__ float inv4[4];
    float acc[4][4];
    #pragma unroll
    for (int ii = 0; ii < 4; ++ii)
        #pragma unroll
        for (int j = 0; j < 4; ++j) acc[ii][j] = 0.f;
    if (i0l < NA) {
        int row = t >> 6, l64 = t & 63;
        float s = 0.f;
        for (int v = l64; v < DV; v += 64) { float x = V[(i0l + row) * DV + v]; s += x * x; }
        #pragma unroll
        for (int o = 32; o; o >>= 1) s += __shfl_xor(s, o, 64);
        if (l64 == 0) inv4[row] = 1.f / fmaxf(sqrtf(s), 1e-12f);
        __syncthreads();
        const float* W  = isQ2 ? W2 : W1;
        const float* Vb = V + (size_t)i0l * DV;
        for (int v = 0; v < DV; v += 2) {
            float4v w0 = *(const float4v*)(W + (size_t)v * CF + t * 4);
            float4v w1 = *(const float4v*)(W + (size_t)(v + 1) * CF + t * 4);
            #pragma unroll
            for (int ii = 0; ii < 4; ++ii) {
                float a0 = Vb[(size_t)ii * DV + v];
                float a1 = Vb[(size_t)ii * DV + v + 1];
                #pragma unroll
                for (int j = 0; j < 4; ++j) acc[ii][j] += a0 * w0[j] + a1 * w1[j];
            }
        }
        #pragma unroll
        for (int ii = 0; ii < 4; ++ii)
            #pragma unroll
            for (int j = 0; j < 4; ++j) acc[ii][j] *= inv4[ii];
    }
    int fg = t >> 3;
    int fo = (t & 7) * 4;
    int q12 = isQ2 ? 1 : 0;
    #pragma unroll
    for (int ii = 0; ii < 4; ++ii) {
        half4 h;
        #pragma unroll
        for (int j = 0; j < 4; ++j) h[j] = (_Float16)acc[ii][j];
        *(half4*)&Qb[((size_t)fg * MT + (2 * (i0l + ii) + q12)) * 32 + fo] = h;
    }
}

// ---- K1: fused norm+transpose+GEMM+partial-softmax. block = (b, r-half). ----
// A (Qb) via global_load_lds DMA; B reg-staged: global f32 -> cvt f16 (+ssq)
// -> ds_write_b128 transposed [fq][r][8f]. All LDS ops b128 conflict-free.
extern __shared__ char smem[];
__launch_bounds__(512, 2)
__global__ void k_fused(const float* __restrict__ img, const _Float16* __restrict__ Qb,
                        float* __restrict__ pm, float* __restrict__ ps,
                        float* __restrict__ pd) {
    int lin = blockIdx.x;          // 0..255
    int b   = lin >> 1;
    int rh  = lin & 1;

    int tid  = threadIdx.x;
    int lane = tid & 63;
    int w    = tid >> 6;           // 0..7
    int wm   = w >> 1;             // 0..3: A rows [wm*160, +160)
    int wn   = w & 1;              // 0..1: cols [wn*64, +64)
    int nl   = lane & 31;
    int kh   = lane >> 5;

    // A: LDS slot s (16B) = kb*640+row; global chunk = (row*4+kb)*16. 5/thread.
    int aG[5];
    #pragma unroll
    for (int j = 0; j < 5; ++j) {
        int s = tid + j * 512;
        aG[j] = ((s % 640) * 4 + (s / 640)) * 16;
    }
    const char* gA = (const char*)Qb;

    // B: thread owns (r = tid&127, fq = tid>>7); 8 f values per kc.
    int rB = tid & 127, fq = tid >> 7;
    const float* gB = img + (size_t)b * CF * RR + (size_t)rh * 128 + rB;

    float16v acc[5][2];
    #pragma unroll
    for (int i = 0; i < 5; ++i)
        #pragma unroll
        for (int j = 0; j < 2; ++j)
            #pragma unroll
            for (int gi = 0; gi < 16; ++gi) acc[i][j][gi] = 0.f;
    float ssq = 0.f;
    float R0[8], R1[8];

    char* buf0 = smem;
    char* buf1 = smem + BUFSZ;

    #define BLOAD(kc_, R) do {                                                     \
        int kcl = (kc_) < NKC ? (kc_) : (NKC - 1);                                 \
        const float* p = gB + ((size_t)kcl * 32 + fq * 8) * RR;                    \
        _Pragma("unroll")                                                          \
        for (int j = 0; j < 8; ++j) (R)[j] = p[(size_t)j * RR];                    \
    } while (0)

    #define AGLL(kc_, buf) do {                                                   \
        int kcl = (kc_) < NKC ? (kc_) : (NKC - 1);                                 \
        const char* aS = gA + (size_t)kcl * ABYTES;                                \
        _Pragma("unroll")                                                          \
        for (int j = 0; j < 5; ++j) gll16(aS + aG[j], (buf) + (tid + j * 512) * 16); \
    } while (0)

    #define CVTW(R, buf) do {                                                      \
        half8 h;                                                                   \
        _Pragma("unroll")                                                          \
        for (int j = 0; j < 8; ++j) {                                              \
            ssq += (R)[j] * (R)[j];                                                \
            h[j] = (_Float16)(R)[j];                                               \
        }                                                                          \
        *(half8*)((buf) + ABYTES + fq * 2048 + rB * 16) = h;                       \
    } while (0)

    #define COMPUTE(buf) do {                                                      \
        const char* Al = (buf); const char* Bl = (buf) + ABYTES;                   \
        int c0 = wn * 64 + nl;                                                     \
        _Pragma("unroll")                                                          \
        for (int ks = 0; ks < 2; ++ks) {                                           \
            int kb = ks * 2 + kh;                                                  \
            half8 bf0 = *(const half8*)(Bl + kb * 2048 + c0 * 16);                 \
            half8 bf1 = *(const half8*)(Bl + kb * 2048 + (c0 + 32) * 16);          \
            _Pragma("unroll")                                                      \
            for (int mt = 0; mt < 5; ++mt) {                                       \
                half8 af = *(const half8*)(Al + ((size_t)kb * 640 + wm * 160 + mt * 32 + nl) * 16); \
                acc[mt][0] = __builtin_amdgcn_mfma_f32_32x32x16_f16(af, bf0, acc[mt][0], 0, 0, 0);  \
                acc[mt][1] = __builtin_amdgcn_mfma_f32_32x32x16_f16(af, bf1, acc[mt][1], 0, 0, 0);  \
            }                                                                      \
        }                                                                          \
    } while (0)

    // prologue: tile0 fully built in buf0; tile1 (A DMA + B regs) in flight
    BLOAD(0, R0);
    AGLL(0, buf0);
    __builtin_amdgcn_sched_barrier(0);
    CVTW(R0, buf0);                        // compiler waits R0 precisely
    BLOAD(1, R1);
    AGLL(1, buf1);
    __builtin_amdgcn_sched_barrier(0);
    asm volatile("s_waitcnt vmcnt(13) lgkmcnt(0)" ::: "memory");  // A(0)+B(0) done
    __builtin_amdgcn_s_barrier();
    __builtin_amdgcn_sched_barrier(0);

    #pragma unroll 1
    for (int kc = 0; kc < NKC; kc += 2) {
        // ---- even tile kc: read buf0; build B(kc+1) into buf1 ----
        BLOAD(kc + 2, R0);                 // full-phase latency cover
        __builtin_amdgcn_sched_barrier(0);
        COMPUTE(buf0);
        __builtin_amdgcn_sched_barrier(0);
        asm volatile("s_waitcnt vmcnt(8)" ::: "memory");   // A(kc+1) landed (FIFO: 5 A before 8 B)
        CVTW(R1, buf1);                    // write B(kc+1)
        asm volatile("s_waitcnt lgkmcnt(0)" ::: "memory");
        __builtin_amdgcn_s_barrier();      // buf1 complete; buf0 released
        __builtin_amdgcn_sched_barrier(0);
        AGLL(kc + 2, buf0);                // A DMA into freed buffer
        __builtin_amdgcn_sched_barrier(0);

        // ---- odd tile kc+1: read buf1; build B(kc+2) into buf0 ----
        BLOAD(kc + 3, R1);
        __builtin_amdgcn_sched_barrier(0);
        COMPUTE(buf1);
        __builtin_amdgcn_sched_barrier(0);
        asm volatile("s_waitcnt vmcnt(8)" ::: "memory");   // A(kc+2) landed
        if (kc + 2 < NKC) CVTW(R0, buf0);  // guard: ssq must not double-count
        asm volatile("s_waitcnt lgkmcnt(0)" ::: "memory");
        __builtin_amdgcn_s_barrier();
        __builtin_amdgcn_sched_barrier(0);
        AGLL(kc + 3, buf1);
        __builtin_amdgcn_sched_barrier(0);
    }
    asm volatile("s_waitcnt vmcnt(0) lgkmcnt(0)" ::: "memory");
    __builtin_amdgcn_s_barrier();
    __builtin_amdgcn_sched_barrier(0);
    #undef BLOAD
    #undef AGLL
    #undef CVTW
    #undef COMPUTE

    // ---- epilogue (aliases buf0) ----
    float* ssq_lds = (float*)smem;               // [512]
    float* ssq_r   = (float*)(smem + 2048);      // [128]
    float* mred    = (float*)(smem + 2560);      // [2][320]
    float* mg      = (float*)(smem + 5120);      // [320]
    float* sred    = (float*)(smem + 6400);      // [2][320]
    float* dred    = (float*)(smem + 8960);      // [2][320]

    ssq_lds[tid] = ssq;
    __syncthreads();
    if (tid < 128)
        ssq_r[tid] = ssq_lds[tid] + ssq_lds[tid + 128] +
                     ssq_lds[tid + 256] + ssq_lds[tid + 384];
    __syncthreads();
    int c0 = wn * 64 + nl;
    float iv0 = 1.f / fmaxf(sqrtf(ssq_r[c0]), 1e-12f);
    float iv1 = 1.f / fmaxf(sqrtf(ssq_r[c0 + 32]), 1e-12f);
    #pragma unroll
    for (int mt = 0; mt < 5; ++mt)
        #pragma unroll
        for (int gi = 0; gi < 16; ++gi) {
            acc[mt][0][gi] *= iv0;
            acc[mt][1][gi] *= iv1;
        }

    // pass 1: per-pair max over this half's 128 r
    #pragma unroll
    for (int mt = 0; mt < 5; ++mt) {
        #pragma unroll
        for (int e = 0; e < 8; ++e) {
            int g = 2 * e;
            float mx = fmaxf(acc[mt][0][g], acc[mt][1][g]);
            #pragma unroll
            for (int off = 1; off <= 16; off <<= 1)
                mx = fmaxf(mx, __shfl_xor(mx, off, 64));
            if (nl == 0) {
                int row = (g & 3) + 8 * (g >> 2) + 4 * kh;     // even, 0..30
                mred[wn * NPI + wm * 80 + mt * 16 + (row >> 1)] = mx;
            }
        }
    }
    __syncthreads();
    if (tid < NPI) mg[tid] = fmaxf(mred[tid], mred[NPI + tid]);
    __syncthreads();

    // pass 2: exp-sum and weighted Q2 dot (local max)
    #pragma unroll
    for (int mt = 0; mt < 5; ++mt) {
        #pragma unroll
        for (int e = 0; e < 8; ++e) {
            int g = 2 * e;
            int row = (g & 3) + 8 * (g >> 2) + 4 * kh;
            int i   = wm * 80 + mt * 16 + (row >> 1);
            float m  = mg[i];
            float e0 = __expf(acc[mt][0][g] - m);
            float e1 = __expf(acc[mt][1][g] - m);
            float s = e0 + e1;
            float d = e0 * acc[mt][0][g + 1] + e1 * acc[mt][1][g + 1];
            #pragma unroll
            for (int off = 1; off <= 16; off <<= 1) {
                s += __shfl_xor(s, off, 64);
                d += __shfl_xor(d, off, 64);
            }
            if (nl == 0) {
                sred[wn * NPI + i] = s;
                dred[wn * NPI + i] = d;
            }
        }
    }
    __syncthreads();
    if (tid < NPI) {
        size_t pb = ((size_t)b * 2 + rh) * NPI + tid;
        pm[pb] = mg[tid];
        ps[pb] = sred[tid] + sred[NPI + tid];
        pd[pb] = dred[tid] + dred[NPI + tid];
    }
}

// ---- K2: combine the two r-halves (flash-style) ----
__launch_bounds__(256, 4)
__global__ void k_comb(const float* __restrict__ pm, const float* __restrict__ ps,
                       const float* __restrict__ pd, float* __restrict__ out) {
    int idx = blockIdx.x * 256 + threadIdx.x;   // 0..40959 = 128*320
    int b = idx / NPI;
    int i = idx - b * NPI;
    float m0 = pm[(size_t)(b * 2) * NPI + i];
    float m1 = pm[(size_t)(b * 2 + 1) * NPI + i];
    float m  = fmaxf(m0, m1);
    float w0 = __expf(m0 - m), w1 = __expf(m1 - m);
    float s = ps[(size_t)(b * 2) * NPI + i] * w0 + ps[(size_t)(b * 2 + 1) * NPI + i] * w1;
    float d = pd[(size_t)(b * 2) * NPI + i] * w0 + pd[(size_t)(b * 2 + 1) * NPI + i] * w1;
    if (i < NA) out[(size_t)b * NA + i] = d / s;
}

// ---- launcher ----
extern "C" void kernel_launch(void* const* d_in, const int* in_sizes, int n_in,
                              void* d_out, int out_size, void* d_ws, size_t ws_size,
                              hipStream_t stream) {
    const float* img = (const float*)d_in[0];
    const float* V   = (const float*)d_in[1];
    const float* W1  = (const float*)d_in[2];
    const float* W2  = (const float*)d_in[3];
    float* out = (float*)d_out;

    char* ws = (char*)d_ws;
    size_t off = 0;
    _Float16* Qb = (_Float16*)(ws + off); off += (size_t)NKC * MT * 32 * 2;
    float*    pm = (float*)(ws + off);    off += (size_t)NB * 2 * NPI * 4;
    float*    ps = (float*)(ws + off);    off += (size_t)NB * 2 * NPI * 4;
    float*    pd = (float*)(ws + off);    off += (size_t)NB * 2 * NPI * 4;

    static bool attr_done = false;
    if (!attr_done) {
        hipFuncSetAttribute((const void*)k_fused,
                            hipFuncAttributeMaxDynamicSharedMemorySize, 2 * BUFSZ);
        attr_done = true;
    }

    k_q<<<dim3(NQ), 256, 0, stream>>>(V, W1, W2, Qb);
    k_fused<<<dim3(256), 512, 2 * BUFSZ, stream>>>(img, Qb, pm, ps, pd);
    k_comb<<<dim3(160), 256, 0, stream>>>(pm, ps, pd, out);
}

// Round 8
// 273.374 us; speedup vs baseline: 1.0082x; 1.0082x over previous
//
#include <hip/hip_runtime.h>
#include <math.h>

#define NB   128
#define CF   1024
#define RR   256
#define NA   312
#define DV   300
#define MT   640
#define NKC  32
#define NQ   160
#define NPI  320          // padded i-pairs
#define ABYTES 40960      // A tile: 640 rows x 64 B (f16)

typedef _Float16 half8  __attribute__((ext_vector_type(8)));
typedef _Float16 half4  __attribute__((ext_vector_type(4)));
typedef float float16v  __attribute__((ext_vector_type(16)));
typedef float float4v   __attribute__((ext_vector_type(4)));

// async global->LDS, 16B/lane; dest = wave-uniform base + lane*16 (linear).
__device__ __forceinline__ void gll16(const void* g, void* l) {
    __builtin_amdgcn_global_load_lds(
        (const __attribute__((address_space(1))) void*)g,
        (__attribute__((address_space(3))) void*)l, 16, 0, 0);
}

// ---- K0: Q projection (pair-interleaved Qb rows: row 2i = Q1_i, 2i+1 = Q2_i) ----
__launch_bounds__(256, 4)
__global__ void k_q(const float* __restrict__ V, const float* __restrict__ W1,
                    const float* __restrict__ W2, _Float16* __restrict__ Qb) {
    int ib = blockIdx.x;
    int t  = threadIdx.x;
    bool isQ2 = ib >= 80;
    int i0l = (ib - (isQ2 ? 80 : 0)) * 4;
    __shared__ float inv4[4];
    float acc[4][4];
    #pragma unroll
    for (int ii = 0; ii < 4; ++ii)
        #pragma unroll
        for (int j = 0; j < 4; ++j) acc[ii][j] = 0.f;
    if (i0l < NA) {
        int row = t >> 6, l64 = t & 63;
        float s = 0.f;
        for (int v = l64; v < DV; v += 64) { float x = V[(i0l + row) * DV + v]; s += x * x; }
        #pragma unroll
        for (int o = 32; o; o >>= 1) s += __shfl_xor(s, o, 64);
        if (l64 == 0) inv4[row] = 1.f / fmaxf(sqrtf(s), 1e-12f);
        __syncthreads();
        const float* W  = isQ2 ? W2 : W1;
        const float* Vb = V + (size_t)i0l * DV;
        for (int v = 0; v < DV; v += 2) {
            float4v w0 = *(const float4v*)(W + (size_t)v * CF + t * 4);
            float4v w1 = *(const float4v*)(W + (size_t)(v + 1) * CF + t * 4);
            #pragma unroll
            for (int ii = 0; ii < 4; ++ii) {
                float a0 = Vb[(size_t)ii * DV + v];
                float a1 = Vb[(size_t)ii * DV + v + 1];
                #pragma unroll
                for (int j = 0; j < 4; ++j) acc[ii][j] += a0 * w0[j] + a1 * w1[j];
            }
        }
        #pragma unroll
        for (int ii = 0; ii < 4; ++ii)
            #pragma unroll
            for (int j = 0; j < 4; ++j) acc[ii][j] *= inv4[ii];
    }
    int fg = t >> 3;
    int fo = (t & 7) * 4;
    int q12 = isQ2 ? 1 : 0;
    #pragma unroll
    for (int ii = 0; ii < 4; ++ii) {
        half4 h;
        #pragma unroll
        for (int j = 0; j < 4; ++j) h[j] = (_Float16)acc[ii][j];
        *(half4*)&Qb[((size_t)fg * MT + (2 * (i0l + ii) + q12)) * 32 + fo] = h;
    }
}

// ---- K1: fused. A (Qb) via LDS DMA (1 barrier/kc, counted vmcnt).        ----
// ---- B fragments loaded per-wave straight to registers (no sync at all). ----
extern __shared__ char smem[];
__launch_bounds__(512, 2)
__global__ void k_fused(const float* __restrict__ img, const _Float16* __restrict__ Qb,
                        float* __restrict__ pm, float* __restrict__ ps,
                        float* __restrict__ pd) {
    int lin = blockIdx.x;          // 0..255
    int b   = lin >> 1;
    int rh  = lin & 1;

    int tid  = threadIdx.x;
    int lane = tid & 63;
    int w    = tid >> 6;           // 0..7
    int wm   = w >> 1;             // 0..3: A rows [wm*160, +160)
    int wn   = w & 1;              // 0..1: cols [wn*64, +64)
    int nl   = lane & 31;
    int kh   = lane >> 5;

    // A staging: LDS slot s (16B units) = kb*640+row; global byte = row*64+kb*16.
    int aG[5];
    #pragma unroll
    for (int j = 0; j < 5; ++j) {
        int s = tid + j * 512;
        aG[j] = ((s % 640) * 4 + (s / 640)) * 16;
    }
    const char* gA = (const char*)Qb;

    // B per-lane: column c_lo = wn*64+nl (and +32); f = kc*32 + kh*8 + ks*16 + j.
    int c_lo = wn * 64 + nl;
    const float* pB = img + (size_t)b * CF * RR + (size_t)rh * 128 + c_lo
                      + (size_t)kh * 8 * RR;

    float16v acc[5][2];
    #pragma unroll
    for (int i = 0; i < 5; ++i)
        #pragma unroll
        for (int j = 0; j < 2; ++j)
            #pragma unroll
            for (int gi = 0; gi < 16; ++gi) acc[i][j][gi] = 0.f;
    float ssq0 = 0.f, ssq1 = 0.f;
    float Bv0[2][8], Bv1[2][8];    // [ks][j], lo / hi column
    half8 bf0[2], bf1[2];

    #define AGLL(kc_, bsel) do {                                                   \
        int kcl = (kc_) < NKC ? (kc_) : (NKC - 1);                                 \
        const char* aS = gA + (size_t)kcl * ABYTES;                                \
        char* buf_ = smem + (size_t)(bsel) * ABYTES;                               \
        _Pragma("unroll")                                                          \
        for (int j = 0; j < 5; ++j) gll16(aS + aG[j], buf_ + (tid + j * 512) * 16); \
    } while (0)

    #define BLOAD(kc_) do {                                                        \
        int kcl = (kc_) < NKC ? (kc_) : (NKC - 1);                                 \
        const float* p = pB + (size_t)kcl * 32 * RR;                               \
        _Pragma("unroll")                                                          \
        for (int ks = 0; ks < 2; ++ks)                                             \
            _Pragma("unroll")                                                      \
            for (int j = 0; j < 8; ++j) {                                          \
                Bv0[ks][j] = p[(size_t)(ks * 16 + j) * RR];                        \
                Bv1[ks][j] = p[(size_t)(ks * 16 + j) * RR + 32];                   \
            }                                                                      \
    } while (0)

    #define BCVT() do {                                                            \
        _Pragma("unroll")                                                          \
        for (int ks = 0; ks < 2; ++ks)                                             \
            _Pragma("unroll")                                                      \
            for (int j = 0; j < 8; ++j) {                                          \
                float x0 = Bv0[ks][j], x1 = Bv1[ks][j];                            \
                ssq0 += x0 * x0; ssq1 += x1 * x1;                                  \
                bf0[ks][j] = (_Float16)x0; bf1[ks][j] = (_Float16)x1;              \
            }                                                                      \
    } while (0)

    #define COMPUTE(bsel) do {                                                     \
        const char* Al = smem + (size_t)(bsel) * ABYTES;                           \
        _Pragma("unroll")                                                          \
        for (int ks = 0; ks < 2; ++ks) {                                           \
            int kb = ks * 2 + kh;                                                  \
            _Pragma("unroll")                                                      \
            for (int mt = 0; mt < 5; ++mt) {                                       \
                half8 af = *(const half8*)(Al + ((size_t)kb * 640 + wm * 160 + mt * 32 + nl) * 16); \
                acc[mt][0] = __builtin_amdgcn_mfma_f32_32x32x16_f16(af, bf0[ks], acc[mt][0], 0, 0, 0); \
                acc[mt][1] = __builtin_amdgcn_mfma_f32_32x32x16_f16(af, bf1[ks], acc[mt][1], 0, 0, 0); \
            }                                                                      \
        }                                                                          \
    } while (0)

    // prologue: establish queue invariant [B(kc) x32 (older), A(kc+1) x5 (younger)]
    AGLL(0, 0);                                        // 5
    BLOAD(0);                                          // +32 -> [A0, B0]
    asm volatile("s_waitcnt vmcnt(32)" ::: "memory");  // A0 landed (oldest 5)
    __builtin_amdgcn_s_barrier();                      // A0 visible to all
    AGLL(1, 1);                                        // -> [B0 32, A1 5]
    __builtin_amdgcn_sched_barrier(0);

    #pragma unroll 1
    for (int kc = 0; kc < NKC; ++kc) {
        asm volatile("s_waitcnt vmcnt(5)" ::: "memory");   // B(kc) landed
        BCVT();
        BLOAD(kc + 1);                                     // -> [A(kc+1) 5, B(kc+1) 32]
        __builtin_amdgcn_sched_barrier(0);
        __builtin_amdgcn_s_setprio(1);
        COMPUTE(kc & 1);
        __builtin_amdgcn_s_setprio(0);
        __builtin_amdgcn_sched_barrier(0);
        asm volatile("s_waitcnt vmcnt(32)" ::: "memory");  // A(kc+1) landed (mine)
        __builtin_amdgcn_s_barrier();                      // all: A(kc+1) ready, buf(kc) free
        AGLL(kc + 2, kc & 1);                              // -> [B(kc+1) 32, A(kc+2) 5]
        __builtin_amdgcn_sched_barrier(0);
    }
    asm volatile("s_waitcnt vmcnt(0) lgkmcnt(0)" ::: "memory");
    __builtin_amdgcn_s_barrier();
    __builtin_amdgcn_sched_barrier(0);
    #undef AGLL
    #undef BLOAD
    #undef BCVT
    #undef COMPUTE

    // ---- epilogue (aliases smem) ----
    float* mred = (float*)smem;                 // [2][320]
    float* mg   = (float*)(smem + 2560);        // [320]
    float* sred = (float*)(smem + 3840);        // [2][320]
    float* dred = (float*)(smem + 6400);        // [2][320]

    // column norms: lane-local sums cover this lane's kh-half of f; merge halves.
    ssq0 += __shfl_xor(ssq0, 32, 64);
    ssq1 += __shfl_xor(ssq1, 32, 64);
    float iv0 = 1.f / fmaxf(sqrtf(ssq0), 1e-12f);
    float iv1 = 1.f / fmaxf(sqrtf(ssq1), 1e-12f);
    #pragma unroll
    for (int mt = 0; mt < 5; ++mt)
        #pragma unroll
        for (int gi = 0; gi < 16; ++gi) {
            acc[mt][0][gi] *= iv0;
            acc[mt][1][gi] *= iv1;
        }

    // pass 1: per-pair max over this half's 128 r
    #pragma unroll
    for (int mt = 0; mt < 5; ++mt) {
        #pragma unroll
        for (int e = 0; e < 8; ++e) {
            int g = 2 * e;
            float mx = fmaxf(acc[mt][0][g], acc[mt][1][g]);
            #pragma unroll
            for (int off = 1; off <= 16; off <<= 1)
                mx = fmaxf(mx, __shfl_xor(mx, off, 64));
            if (nl == 0) {
                int row = (g & 3) + 8 * (g >> 2) + 4 * kh;     // even, 0..30
                mred[wn * NPI + wm * 80 + mt * 16 + (row >> 1)] = mx;
            }
        }
    }
    __syncthreads();
    if (tid < NPI) mg[tid] = fmaxf(mred[tid], mred[NPI + tid]);
    __syncthreads();

    // pass 2: exp-sum and weighted Q2 dot (local max)
    #pragma unroll
    for (int mt = 0; mt < 5; ++mt) {
        #pragma unroll
        for (int e = 0; e < 8; ++e) {
            int g = 2 * e;
            int row = (g & 3) + 8 * (g >> 2) + 4 * kh;
            int i   = wm * 80 + mt * 16 + (row >> 1);
            float m  = mg[i];
            float e0 = __expf(acc[mt][0][g] - m);
            float e1 = __expf(acc[mt][1][g] - m);
            float s = e0 + e1;
            float d = e0 * acc[mt][0][g + 1] + e1 * acc[mt][1][g + 1];
            #pragma unroll
            for (int off = 1; off <= 16; off <<= 1) {
                s += __shfl_xor(s, off, 64);
                d += __shfl_xor(d, off, 64);
            }
            if (nl == 0) {
                sred[wn * NPI + i] = s;
                dred[wn * NPI + i] = d;
            }
        }
    }
    __syncthreads();
    if (tid < NPI) {
        size_t pb = ((size_t)b * 2 + rh) * NPI + tid;
        pm[pb] = mg[tid];
        ps[pb] = sred[tid] + sred[NPI + tid];
        pd[pb] = dred[tid] + dred[NPI + tid];
    }
}

// ---- K2: combine the two r-halves (flash-style) ----
__launch_bounds__(256, 4)
__global__ void k_comb(const float* __restrict__ pm, const float* __restrict__ ps,
                       const float* __restrict__ pd, float* __restrict__ out) {
    int idx = blockIdx.x * 256 + threadIdx.x;   // 0..40959 = 128*320
    int b = idx / NPI;
    int i = idx - b * NPI;
    float m0 = pm[(size_t)(b * 2) * NPI + i];
    float m1 = pm[(size_t)(b * 2 + 1) * NPI + i];
    float m  = fmaxf(m0, m1);
    float w0 = __expf(m0 - m), w1 = __expf(m1 - m);
    float s = ps[(size_t)(b * 2) * NPI + i] * w0 + ps[(size_t)(b * 2 + 1) * NPI + i] * w1;
    float d = pd[(size_t)(b * 2) * NPI + i] * w0 + pd[(size_t)(b * 2 + 1) * NPI + i] * w1;
    if (i < NA) out[(size_t)b * NA + i] = d / s;
}

// ---- launcher ----
extern "C" void kernel_launch(void* const* d_in, const int* in_sizes, int n_in,
                              void* d_out, int out_size, void* d_ws, size_t ws_size,
                              hipStream_t stream) {
    const float* img = (const float*)d_in[0];
    const float* V   = (const float*)d_in[1];
    const float* W1  = (const float*)d_in[2];
    const float* W2  = (const float*)d_in[3];
    float* out = (float*)d_out;

    char* ws = (char*)d_ws;
    size_t off = 0;
    _Float16* Qb = (_Float16*)(ws + off); off += (size_t)NKC * MT * 32 * 2;
    float*    pm = (float*)(ws + off);    off += (size_t)NB * 2 * NPI * 4;
    float*    ps = (float*)(ws + off);    off += (size_t)NB * 2 * NPI * 4;
    float*    pd = (float*)(ws + off);    off += (size_t)NB * 2 * NPI * 4;

    static bool attr_done = false;
    if (!attr_done) {
        (void)hipFuncSetAttribute((const void*)k_fused,
                                  hipFuncAttributeMaxDynamicSharedMemorySize, 2 * ABYTES);
        attr_done = true;
    }

    k_q<<<dim3(NQ), 256, 0, stream>>>(V, W1, W2, Qb);
    k_fused<<<dim3(256), 512, 2 * ABYTES, stream>>>(img, Qb, pm, ps, pd);
    k_comb<<<dim3(160), 256, 0, stream>>>(pm, ps, pd, out);
}